// Round 2
// baseline (100.235 us; speedup 1.0000x reference)
//
#include <hip/hip_runtime.h>
#include <math.h>

#define NBINS 100
static constexpr float LM1f  = -4.605170185988091f;  // log(0.01)
static constexpr float LM2f  =  5.991464547107982f;  // log(400)
static constexpr float EPSV  = 1e-5f;
static constexpr float BETA  = 0.1f;

// Workspace layout (uint32 units): [0]=sumsq(float), [1..100]=hist_pred, [101..200]=hist_act
// Kernel 1: streaming MSE partial sums + per-wave LDS histograms -> global atomics.
__global__ __launch_bounds__(256) void mse_hist_kernel(
    const float4* __restrict__ pred, const float4* __restrict__ act,
    long long n4, long long ntail, const float* __restrict__ pred_s,
    const float* __restrict__ act_s,
    float* __restrict__ sumsq, unsigned int* __restrict__ hp,
    unsigned int* __restrict__ ha)
{
    __shared__ unsigned int sh[4][2 * NBINS];   // per-wave privatized histograms
    const int wave = threadIdx.x >> 6;

    for (int i = threadIdx.x; i < 4 * 2 * NBINS; i += blockDim.x)
        ((unsigned int*)sh)[i] = 0u;
    __syncthreads();

    const float scale = (float)NBINS / (LM2f - LM1f);
    unsigned int* mh = sh[wave];

    float acc = 0.f;
    long long idx    = (long long)blockIdx.x * blockDim.x + threadIdx.x;
    long long stride = (long long)gridDim.x * blockDim.x;

    for (long long i = idx; i < n4; i += stride) {
        float4 p = pred[i];
        float4 a = act[i];
        float d0 = p.x - a.x, d1 = p.y - a.y, d2 = p.z - a.z, d3 = p.w - a.w;
        acc += d0 * d0 + d1 * d1 + d2 * d2 + d3 * d3;

        float vals[8] = {p.x, p.y, p.z, p.w, a.x, a.y, a.z, a.w};
        #pragma unroll
        for (int j = 0; j < 8; ++j) {
            float x = vals[j];
            if (x >= LM1f && x <= LM2f) {
                int b = (int)((x - LM1f) * scale);
                if (b > NBINS - 1) b = NBINS - 1;
                atomicAdd(&mh[(j >= 4 ? NBINS : 0) + b], 1u);
            }
        }
    }

    // Tail (n not divisible by 4) — handled by thread 0 of block 0.
    if (blockIdx.x == 0 && threadIdx.x == 0) {
        for (long long i = 0; i < ntail; ++i) {
            float p = pred_s[4 * n4 + i];
            float a = act_s[4 * n4 + i];
            float d = p - a;
            acc += d * d;
            float v2[2] = {p, a};
            for (int j = 0; j < 2; ++j) {
                float x = v2[j];
                if (x >= LM1f && x <= LM2f) {
                    int b = (int)((x - LM1f) * scale);
                    if (b > NBINS - 1) b = NBINS - 1;
                    atomicAdd(&mh[(j == 1 ? NBINS : 0) + b], 1u);
                }
            }
        }
    }
    __syncthreads();

    // Reduce the 4 wave copies and push to global histograms.
    for (int i = threadIdx.x; i < 2 * NBINS; i += blockDim.x) {
        unsigned int s = sh[0][i] + sh[1][i] + sh[2][i] + sh[3][i];
        if (s) {
            if (i < NBINS) atomicAdd(&hp[i], s);
            else           atomicAdd(&ha[i - NBINS], s);
        }
    }

    // Block-reduce the squared-diff accumulator (wave=64 shuffle).
    for (int off = 32; off > 0; off >>= 1)
        acc += __shfl_down(acc, off);
    __shared__ float wsum[4];
    if ((threadIdx.x & 63) == 0) wsum[wave] = acc;
    __syncthreads();
    if (threadIdx.x == 0)
        atomicAdd(sumsq, wsum[0] + wsum[1] + wsum[2] + wsum[3]);
}

// Kernel 2: normalize histograms, KLD, combine with MSE. One block, 128 threads.
__global__ __launch_bounds__(128) void finalize_kernel(
    const float* __restrict__ sumsq, const unsigned int* __restrict__ hp,
    const unsigned int* __restrict__ ha, float* __restrict__ out, float n_elems)
{
    const int t = threadIdx.x;
    float hpv = 0.f, hav = 0.f;
    if (t < NBINS) {
        hpv = (float)hp[t] + EPSV;
        hav = (float)ha[t] + EPSV;
    }

    // Block sums of hpv/hav (2 waves).
    float sp = hpv, sa = hav;
    for (int off = 32; off > 0; off >>= 1) {
        sp += __shfl_down(sp, off);
        sa += __shfl_down(sa, off);
    }
    __shared__ float shp[2], sha[2];
    if ((t & 63) == 0) { shp[t >> 6] = sp; sha[t >> 6] = sa; }
    __syncthreads();
    const float tot_p = shp[0] + shp[1];
    const float tot_a = sha[0] + sha[1];

    float term = 0.f;
    if (t < NBINS) {
        float pv = hpv / tot_p;
        float av = hav / tot_a;
        term = av * (logf(av) - logf(pv));
    }
    for (int off = 32; off > 0; off >>= 1)
        term += __shfl_down(term, off);
    __shared__ float st[2];
    if ((t & 63) == 0) st[t >> 6] = term;
    __syncthreads();
    if (t == 0) {
        float kld = (st[0] + st[1]) / (float)NBINS;
        out[0] = sumsq[0] / n_elems + BETA * kld;
    }
}

extern "C" void kernel_launch(void* const* d_in, const int* in_sizes, int n_in,
                              void* d_out, int out_size, void* d_ws, size_t ws_size,
                              hipStream_t stream) {
    const float* pred = (const float*)d_in[0];
    const float* act  = (const float*)d_in[1];
    const long long n  = (long long)in_sizes[0];
    const long long n4 = n / 4;
    const long long ntail = n - 4 * n4;

    float*        sumsq = (float*)d_ws;
    unsigned int* hp    = (unsigned int*)d_ws + 1;
    unsigned int* ha    = (unsigned int*)d_ws + 1 + NBINS;

    hipMemsetAsync(d_ws, 0, (1 + 2 * NBINS) * sizeof(unsigned int), stream);

    const int blocks = 2048;   // 8 blocks/CU, grid-stride covers the rest
    mse_hist_kernel<<<blocks, 256, 0, stream>>>(
        (const float4*)pred, (const float4*)act, n4, ntail, pred, act,
        sumsq, hp, ha);

    finalize_kernel<<<1, 128, 0, stream>>>(sumsq, hp, ha, (float*)d_out, (float)n);
}

// Round 3
// 94.203 us; speedup vs baseline: 1.0640x; 1.0640x over previous
//
#include <hip/hip_runtime.h>
#include <math.h>

#define NBINS 100
#define NCOPY 16   // bin-major sub-histogram copies: addr = bin*NCOPY + (lane&15)
static constexpr float LM1f  = -4.605170185988091f;  // log(0.01)
static constexpr float LM2f  =  5.991464547107982f;  // log(400)
static constexpr float EPSV  = 1e-5f;
static constexpr float BETA  = 0.1f;

// Workspace (uint32 units): [0]=sumsq(float), [1..100]=hist_pred, [101..200]=hist_act
__global__ __launch_bounds__(256) void mse_hist_kernel(
    const float4* __restrict__ pred4, const float4* __restrict__ act4,
    const float* __restrict__ pred_s, const float* __restrict__ act_s,
    long long n,
    float* __restrict__ sumsq, unsigned int* __restrict__ hp,
    unsigned int* __restrict__ ha)
{
    // 2 hists * 100 bins * 16 copies * 4B = 12.8 KB
    __shared__ unsigned int sh[2 * NBINS * NCOPY];
    for (int i = threadIdx.x; i < 2 * NBINS * NCOPY; i += blockDim.x)
        sh[i] = 0u;
    __syncthreads();

    const int   c     = threadIdx.x & (NCOPY - 1);
    const float scale = (float)NBINS / (LM2f - LM1f);
    unsigned int* __restrict__ shp = sh;                 // pred hist
    unsigned int* __restrict__ sha = sh + NBINS * NCOPY; // actual hist

    float acc = 0.f;
    const long long n4 = n >> 2;   // float4 count
    const long long n8 = n4 >> 1;  // pairs of float4
    long long idx    = (long long)blockIdx.x * blockDim.x + threadIdx.x;
    long long stride = (long long)gridDim.x * blockDim.x;

#define HVAL(xv, base) do {                                       \
        float x_ = (xv);                                          \
        if (x_ >= LM1f && x_ <= LM2f) {                           \
            int b_ = (int)((x_ - LM1f) * scale);                  \
            if (b_ > NBINS - 1) b_ = NBINS - 1;                   \
            atomicAdd(&base[b_ * NCOPY + c], 1u);                 \
        }                                                         \
    } while (0)

    for (long long i = idx; i < n8; i += stride) {
        // 32B/thread contiguous: 4 x dwordx4, batched for ILP
        float4 p0 = pred4[2 * i];
        float4 p1 = pred4[2 * i + 1];
        float4 a0 = act4[2 * i];
        float4 a1 = act4[2 * i + 1];

        float d;
        d = p0.x - a0.x; acc += d * d;
        d = p0.y - a0.y; acc += d * d;
        d = p0.z - a0.z; acc += d * d;
        d = p0.w - a0.w; acc += d * d;
        d = p1.x - a1.x; acc += d * d;
        d = p1.y - a1.y; acc += d * d;
        d = p1.z - a1.z; acc += d * d;
        d = p1.w - a1.w; acc += d * d;

        HVAL(p0.x, shp); HVAL(p0.y, shp); HVAL(p0.z, shp); HVAL(p0.w, shp);
        HVAL(p1.x, shp); HVAL(p1.y, shp); HVAL(p1.z, shp); HVAL(p1.w, shp);
        HVAL(a0.x, sha); HVAL(a0.y, sha); HVAL(a0.z, sha); HVAL(a0.w, sha);
        HVAL(a1.x, sha); HVAL(a1.y, sha); HVAL(a1.z, sha); HVAL(a1.w, sha);
    }

    // Leftover float4 (n4 odd) + scalar tail — thread 0 of block 0.
    if (blockIdx.x == 0 && threadIdx.x == 0) {
        for (long long j = 2 * n8; j < n4; ++j) {
            float4 p = pred4[j], a = act4[j];
            float d;
            d = p.x - a.x; acc += d * d;
            d = p.y - a.y; acc += d * d;
            d = p.z - a.z; acc += d * d;
            d = p.w - a.w; acc += d * d;
            HVAL(p.x, shp); HVAL(p.y, shp); HVAL(p.z, shp); HVAL(p.w, shp);
            HVAL(a.x, sha); HVAL(a.y, sha); HVAL(a.z, sha); HVAL(a.w, sha);
        }
        for (long long j = 4 * n4; j < n; ++j) {
            float p = pred_s[j], a = act_s[j];
            float d = p - a; acc += d * d;
            HVAL(p, shp);
            HVAL(a, sha);
        }
    }
#undef HVAL
    __syncthreads();

    // Collapse the 16 copies per bin; push to global histograms.
    for (int bin = threadIdx.x; bin < 2 * NBINS; bin += blockDim.x) {
        unsigned int s = 0;
        const unsigned int* p = sh + bin * NCOPY;
        #pragma unroll
        for (int k = 0; k < NCOPY; ++k) s += p[k];
        if (s) {
            if (bin < NBINS) atomicAdd(&hp[bin], s);
            else             atomicAdd(&ha[bin - NBINS], s);
        }
    }

    // Block-reduce squared-diff (wave64 shuffle, then LDS).
    for (int off = 32; off > 0; off >>= 1)
        acc += __shfl_down(acc, off);
    __shared__ float wsum[4];
    if ((threadIdx.x & 63) == 0) wsum[threadIdx.x >> 6] = acc;
    __syncthreads();
    if (threadIdx.x == 0)
        atomicAdd(sumsq, wsum[0] + wsum[1] + wsum[2] + wsum[3]);
}

// Kernel 2: normalize histograms, KLD, combine with MSE. One block, 128 threads.
__global__ __launch_bounds__(128) void finalize_kernel(
    const float* __restrict__ sumsq, const unsigned int* __restrict__ hp,
    const unsigned int* __restrict__ ha, float* __restrict__ out, float n_elems)
{
    const int t = threadIdx.x;
    float hpv = 0.f, hav = 0.f;
    if (t < NBINS) {
        hpv = (float)hp[t] + EPSV;
        hav = (float)ha[t] + EPSV;
    }

    float sp = hpv, sa = hav;
    for (int off = 32; off > 0; off >>= 1) {
        sp += __shfl_down(sp, off);
        sa += __shfl_down(sa, off);
    }
    __shared__ float shp[2], sha[2];
    if ((t & 63) == 0) { shp[t >> 6] = sp; sha[t >> 6] = sa; }
    __syncthreads();
    const float tot_p = shp[0] + shp[1];
    const float tot_a = sha[0] + sha[1];

    float term = 0.f;
    if (t < NBINS) {
        float pv = hpv / tot_p;
        float av = hav / tot_a;
        term = av * (logf(av) - logf(pv));
    }
    for (int off = 32; off > 0; off >>= 1)
        term += __shfl_down(term, off);
    __shared__ float st[2];
    if ((t & 63) == 0) st[t >> 6] = term;
    __syncthreads();
    if (t == 0) {
        float kld = (st[0] + st[1]) / (float)NBINS;
        out[0] = sumsq[0] / n_elems + BETA * kld;
    }
}

extern "C" void kernel_launch(void* const* d_in, const int* in_sizes, int n_in,
                              void* d_out, int out_size, void* d_ws, size_t ws_size,
                              hipStream_t stream) {
    const float* pred = (const float*)d_in[0];
    const float* act  = (const float*)d_in[1];
    const long long n = (long long)in_sizes[0];

    float*        sumsq = (float*)d_ws;
    unsigned int* hp    = (unsigned int*)d_ws + 1;
    unsigned int* ha    = (unsigned int*)d_ws + 1 + NBINS;

    hipMemsetAsync(d_ws, 0, (1 + 2 * NBINS) * sizeof(unsigned int), stream);

    const int blocks = 2048;   // 8 blocks/CU at 256 threads; LDS 12.8 KB/block
    mse_hist_kernel<<<blocks, 256, 0, stream>>>(
        (const float4*)pred, (const float4*)act, pred, act, n,
        sumsq, hp, ha);

    finalize_kernel<<<1, 128, 0, stream>>>(sumsq, hp, ha, (float*)d_out, (float)n);
}